// Round 1
// baseline (819.534 us; speedup 1.0000x reference)
//
#include <hip/hip_runtime.h>

// Net_23484881175023: conv1d(k=3,stride=3) -> LSTM(input=1, hidden=10, T=8192) -> Linear(10,3)
// B=512, L=24576, Lp=8192.
//
// Latency-bound sequential recurrence. One wave per batch element (512 waves,
// ~1 wave/SIMD on 256 CUs). Lane layout: lane = hid*4 + gate_type (40 active
// lanes), so i,f,g,o of hidden unit h live in quad {4h..4h+3}:
//   - h broadcast for the W_hh dot product: v_readlane (uniform lane idx -> SGPR)
//   - i/f/g/o gather: DPP quad_perm broadcasts (VALU-latency, no LDS pipe)
//   - tanh folded as 2*sigmoid(2x)-1; the *2 scale is a per-lane constant on the
//     exp argument, the 2s-1 is folded into the cell/h update FMAs.

#define DEV __device__ __forceinline__

DEV float rl_f(float v, int lane) {
  return __int_as_float(__builtin_amdgcn_readlane(__float_as_int(v), lane));
}

template <int CTRL>
DEV float quad_bcast(float v) {
#if __has_builtin(__builtin_amdgcn_mov_dpp)
  return __int_as_float(__builtin_amdgcn_mov_dpp(__float_as_int(v), CTRL, 0xF, 0xF, true));
#else
  return __int_as_float(__builtin_amdgcn_update_dpp(0, __float_as_int(v), CTRL, 0xF, 0xF, true));
#endif
}

DEV float fast_exp2(float x) {
#if __has_builtin(__builtin_amdgcn_exp2f)
  return __builtin_amdgcn_exp2f(x);
#else
  return __exp2f(x);
#endif
}

DEV float fast_rcp(float x) { return __builtin_amdgcn_rcpf(x); }

constexpr int kB = 512;
constexpr int kL = 24576;
constexpr int kLp = 8192;      // kL / 3
constexpr int kHid = 10;
constexpr int kChunk = 64;     // timesteps per chunk (one ct per lane)
constexpr int kNChunk = kLp / kChunk;  // 128

__global__ __launch_bounds__(256, 1) void lstm_fused(
    const float* __restrict__ x,       // (B, L, 1)
    const float* __restrict__ conv_w,  // (1,1,3)
    const float* __restrict__ conv_b,  // (1,)
    const float* __restrict__ w_ih,    // (40,1)
    const float* __restrict__ w_hh,    // (40,10)
    const float* __restrict__ b_ih,    // (40,)
    const float* __restrict__ b_hh,    // (40,)
    const float* __restrict__ mlp_w,   // (3,10)
    const float* __restrict__ mlp_b,   // (3,)
    float* __restrict__ out) {         // (B,3)
  const int lane = threadIdx.x & 63;
  const int wave = threadIdx.x >> 6;
  const int b = blockIdx.x * 4 + wave;

  const int hid = lane >> 2;   // 0..9 for active lanes
  const int gt = lane & 3;     // 0:i 1:f 2:g 3:o (torch gate order)
  const bool active = (lane < 40);
  const int r = active ? (gt * kHid + hid) : 0;  // row in the 4H-stacked weights

  // uniform conv params (scalar loads)
  const float cw0 = conv_w[0], cw1 = conv_w[1], cw2 = conv_w[2];
  const float cbv = conv_b[0];

  // per-lane gate-row params
  const float wih = w_ih[r];
  const float bsum = b_ih[r] + b_hh[r];
  const float* wr = w_hh + r * kHid;
  const float w0 = wr[0], w1 = wr[1], w2 = wr[2], w3 = wr[3], w4 = wr[4];
  const float w5 = wr[5], w6 = wr[6], w7 = wr[7], w8 = wr[8], w9 = wr[9];

  constexpr float kL2E = 1.4426950408889634f;  // log2(e)
  // gate g uses sigmoid(2x) (tanh folding); i/f/o use sigmoid(x)
  const float smul = (gt == 2) ? (-2.0f * kL2E) : (-kL2E);

  const float* xb = x + (size_t)b * kL;
  const int xoff = lane * 3;

  // prefetch chunk 0's x values
  float x0 = xb[xoff + 0];
  float x1 = xb[xoff + 1];
  float x2 = xb[xoff + 2];

  float h = 0.0f;    // lane's quad value of h[hid]
  float cst = 0.0f;  // lane's quad value of c[hid]

  for (int ch = 0; ch < kNChunk; ++ch) {
    // conv output for timestep (ch*64 + lane), all 64 lanes
    float ct = fmaf(x2, cw2, fmaf(x1, cw1, fmaf(x0, cw0, cbv)));
    ct = fmaxf(ct, 0.0f);

    // prefetch next chunk (consumed after the 64-step inner loop)
    if (ch + 1 < kNChunk) {
      const float* xn = xb + (size_t)(ch + 1) * (kChunk * 3) + xoff;
      x0 = xn[0];
      x1 = xn[1];
      x2 = xn[2];
    }

#pragma unroll 8
    for (int t = 0; t < kChunk; ++t) {
      // input-side preactivation (off critical path)
      const float ctv = rl_f(ct, t);
      const float xg = fmaf(ctv, wih, bsum);

      // dot(h, w_hh[r]) via readlane broadcasts, 2 accumulator chains
      float p0 = fmaf(rl_f(h, 0), w0, xg);
      p0 = fmaf(rl_f(h, 4), w1, p0);
      p0 = fmaf(rl_f(h, 8), w2, p0);
      p0 = fmaf(rl_f(h, 12), w3, p0);
      p0 = fmaf(rl_f(h, 16), w4, p0);
      float p1 = rl_f(h, 20) * w5;
      p1 = fmaf(rl_f(h, 24), w6, p1);
      p1 = fmaf(rl_f(h, 28), w7, p1);
      p1 = fmaf(rl_f(h, 32), w8, p1);
      p1 = fmaf(rl_f(h, 36), w9, p1);
      const float pre = p0 + p1;

      // unified activation: a = sigmoid(pre) for i/f/o, sigmoid(2*pre) for g
      const float a = fast_rcp(1.0f + fast_exp2(pre * smul));

      // gather the quad's i,f,g,o (every lane, redundant across the quad)
      const float iv = quad_bcast<0x00>(a);
      const float fv = quad_bcast<0x55>(a);
      const float gv = quad_bcast<0xAA>(a);  // sigma(2g); tanh(g) = 2*gv - 1
      const float ov = quad_bcast<0xFF>(a);

      // c = f*c + i*tanh(g) = f*c + (2*i*gv - i)
      const float u = fmaf(iv * gv, 2.0f, -iv);
      cst = fmaf(fv, cst, u);

      // h = o * tanh(c) = 2*o*sigma(2c) - o
      const float s2 = fast_rcp(1.0f + fast_exp2(cst * (-2.0f * kL2E)));
      h = fmaf(ov * s2, 2.0f, -ov);
    }
  }

  // epilogue: out[b][m] = sum_k h[k]*mlp_w[m][k] + mlp_b[m], m = 0..2
  if (lane < 3) {
    const float* mw = mlp_w + lane * kHid;
    float acc = mlp_b[lane];
    acc = fmaf(rl_f(h, 0), mw[0], acc);
    acc = fmaf(rl_f(h, 4), mw[1], acc);
    acc = fmaf(rl_f(h, 8), mw[2], acc);
    acc = fmaf(rl_f(h, 12), mw[3], acc);
    acc = fmaf(rl_f(h, 16), mw[4], acc);
    acc = fmaf(rl_f(h, 20), mw[5], acc);
    acc = fmaf(rl_f(h, 24), mw[6], acc);
    acc = fmaf(rl_f(h, 28), mw[7], acc);
    acc = fmaf(rl_f(h, 32), mw[8], acc);
    acc = fmaf(rl_f(h, 36), mw[9], acc);
    out[b * 3 + lane] = acc;
  }
}

extern "C" void kernel_launch(void* const* d_in, const int* in_sizes, int n_in,
                              void* d_out, int out_size, void* d_ws, size_t ws_size,
                              hipStream_t stream) {
  const float* x = (const float*)d_in[0];
  const float* conv_w = (const float*)d_in[1];
  const float* conv_b = (const float*)d_in[2];
  const float* w_ih = (const float*)d_in[3];
  const float* w_hh = (const float*)d_in[4];
  const float* b_ih = (const float*)d_in[5];
  const float* b_hh = (const float*)d_in[6];
  const float* mlp_w = (const float*)d_in[7];
  const float* mlp_b = (const float*)d_in[8];
  float* out = (float*)d_out;

  // 128 blocks x 256 threads = 512 waves; one wave per batch element.
  // 4 waves/block land on the 4 SIMDs of a CU -> ~1 wave/SIMD chip-wide.
  dim3 grid(kB / 4), block(256);
  hipLaunchKernelGGL(lstm_fused, grid, block, 0, stream, x, conv_w, conv_b,
                     w_ih, w_hh, b_ih, b_hh, mlp_w, mlp_b, out);
}